// Round 1
// baseline (421.232 us; speedup 1.0000x reference)
//
#include <hip/hip_runtime.h>

// MoE forward: shared SwiGLU expert + top-2/8 routed SwiGLU experts + aux loss.
// R7: all GEMMs moved to 256x256x64 8-wave 8-PHASE counted-vmcnt template
// (T3+T4+T5 per catalog). Wg/Wu interleaved (16-col blocks) into WguT so
// gate+up is ONE GEMM with SwiGLU fused in epilogue. Routed pad 128->256,
// meta early-exit for dummy tiles. XOR chunk swizzle kept (0 conflicts).

typedef unsigned short u16;
typedef unsigned int   u32;
typedef short short8 __attribute__((ext_vector_type(8)));
typedef float f32x4  __attribute__((ext_vector_type(4)));

#define AS1 __attribute__((address_space(1)))
#define AS3 __attribute__((address_space(3)))

constexpr int T  = 8192;
constexpr int H  = 1024;
constexpr int E  = 8;
constexpr int D  = 512;
constexpr int DS = 1024;          // shared expert width
constexpr int PAIR_CAP  = 18432;  // 72*256 >= 16384 + 8*255, 256-aligned
constexpr int MT_ROUTED = 72;     // routed m-tiles (256 rows each)
constexpr int RB = 512;           // router blocks (16 tokens each)

constexpr int GU_ROUTED_BLKS = 4 * MT_ROUTED;   // 288 (N=1024 interleaved -> 4 ntiles)
constexpr int GU_SHARED_BLKS = 8 * (T / 256);   // 256 (N=2048 interleaved -> 8 ntiles)
constexpr int DR_BLKS = 4 * MT_ROUTED;          // 288 (N=1024 -> 4 ntiles)
constexpr int DSH_BLKS = 4 * (T / 256);         // 128 (N=1024 -> 4 ntiles)

__device__ __forceinline__ u16 f2bf(float f){
  u32 u = __builtin_bit_cast(u32, f);
  u += 0x7fffu + ((u >> 16) & 1u);   // round-to-nearest-even
  return (u16)(u >> 16);
}
__device__ __forceinline__ float bf2f(u16 h){
  u32 u = ((u32)h) << 16;
  return __builtin_bit_cast(float, u);
}

// async global->LDS, 16B per lane. LDS dest = wave-uniform base + lane*16.
__device__ __forceinline__ void gl_lds16(const u16* g, u16* l){
  __builtin_amdgcn_global_load_lds((const AS1 void*)g, (AS3 void*)l, 16, 0, 0);
}

// s_waitcnt imm: vm[3:0] | exp=7<<4 | lgkm=15<<8
__device__ __forceinline__ void wait_vmcnt4(){ __builtin_amdgcn_s_waitcnt(0x0f74); }
__device__ __forceinline__ void wait_vmcnt0(){ __builtin_amdgcn_s_waitcnt(0x0f70); }

// workgroup barrier with LDS-only ordering (no global vmcnt drain)
__device__ __forceinline__ void bar_sync(){
  __builtin_amdgcn_fence(__ATOMIC_RELEASE, "workgroup", "local");
  __builtin_amdgcn_s_barrier();
  __builtin_amdgcn_fence(__ATOMIC_ACQUIRE, "workgroup", "local");
}

// Fragment read offset (elems) for logical chunk c at a row with row&7==lane&7.
__device__ __forceinline__ int swz_off(int c, int lane){
  return ((c ^ (lane & 7)) * 8);
}

// ---------------- router: logits -> softmax -> top2 + bf16 convert of x -----
__global__ void __launch_bounds__(256) router_kernel(
    const float* __restrict__ x, const float* __restrict__ Wr,
    u16* __restrict__ xb,
    int* __restrict__ topk_idx, float* __restrict__ topk_w,
    int* __restrict__ partial_hist, float* __restrict__ partial_probs)
{
  __shared__ int   hist_s[4][8];
  __shared__ float ps_s[4][8];
  int tid = threadIdx.x, lane = tid & 63, wv = tid >> 6;
  int   histl[8] = {0,0,0,0,0,0,0,0};
  float psl[8]   = {0.f,0.f,0.f,0.f,0.f,0.f,0.f,0.f};

  for (int it = 0; it < 4; ++it){
    int t = blockIdx.x * 16 + wv * 4 + it;
    const float4* xr = (const float4*)(x + (long)t * H);
    uint2* xbr = (uint2*)(xb + (long)t * H);
    float acc[8];
#pragma unroll
    for (int e = 0; e < 8; ++e) acc[e] = 0.f;
#pragma unroll
    for (int i = 0; i < 4; ++i){
      float4 xv = xr[i * 64 + lane];
      u32 lo = (u32)f2bf(xv.x) | ((u32)f2bf(xv.y) << 16);
      u32 hi = (u32)f2bf(xv.z) | ((u32)f2bf(xv.w) << 16);
      xbr[i * 64 + lane] = make_uint2(lo, hi);
      int h0 = i * 256 + lane * 4;
#pragma unroll
      for (int j = 0; j < 4; ++j){
        float xs = (j == 0) ? xv.x : (j == 1) ? xv.y : (j == 2) ? xv.z : xv.w;
        const float4* wr = (const float4*)(Wr + (long)(h0 + j) * E);
        float4 w0 = wr[0], w1 = wr[1];
        acc[0] += xs * w0.x; acc[1] += xs * w0.y; acc[2] += xs * w0.z; acc[3] += xs * w0.w;
        acc[4] += xs * w1.x; acc[5] += xs * w1.y; acc[6] += xs * w1.z; acc[7] += xs * w1.w;
      }
    }
#pragma unroll
    for (int off = 32; off >= 1; off >>= 1){
#pragma unroll
      for (int e = 0; e < 8; ++e) acc[e] += __shfl_xor(acc[e], off, 64);
    }
    if (lane == 0){
      float m = acc[0];
#pragma unroll
      for (int e = 1; e < 8; ++e) m = fmaxf(m, acc[e]);
      float p[8], s = 0.f;
#pragma unroll
      for (int e = 0; e < 8; ++e){ p[e] = __expf(acc[e] - m); s += p[e]; }
      float inv = 1.f / s;
#pragma unroll
      for (int e = 0; e < 8; ++e) psl[e] += p[e] * inv;
      int i1 = 0; float v1 = p[0];
#pragma unroll
      for (int e = 1; e < 8; ++e) if (p[e] > v1){ v1 = p[e]; i1 = e; }
      int i2 = -1; float v2 = -1.f;
#pragma unroll
      for (int e = 0; e < 8; ++e) if (e != i1 && p[e] > v2){ v2 = p[e]; i2 = e; }
      float rs = 1.f / (v1 + v2);
      topk_idx[2 * t] = i1; topk_idx[2 * t + 1] = i2;
      topk_w[2 * t] = v1 * rs; topk_w[2 * t + 1] = v2 * rs;
      histl[i1]++; histl[i2]++;
    }
  }
  if (lane == 0){
#pragma unroll
    for (int e = 0; e < 8; ++e){ hist_s[wv][e] = histl[e]; ps_s[wv][e] = psl[e]; }
  }
  __syncthreads();
  if (tid < 8){
    int hs = 0; float ps = 0.f;
#pragma unroll
    for (int w = 0; w < 4; ++w){ hs += hist_s[w][tid]; ps += ps_s[w][tid]; }
    partial_hist[blockIdx.x * 8 + tid]  = hs;
    partial_probs[blockIdx.x * 8 + tid] = ps;
  }
}

// ---------------- scan: 256-padded bases + per-block offsets + aux loss ------
__global__ void __launch_bounds__(64) scan_kernel(
    const int* __restrict__ partial_hist, const float* __restrict__ partial_probs,
    int* __restrict__ block_offset, float* __restrict__ out_aux,
    int* __restrict__ meta)
{
  __shared__ int   csum[8][8];
  __shared__ float cps[8][8];
  __shared__ int   cbase[8][8];
  __shared__ int   base_s[8];
  int tid = threadIdx.x, e = tid & 7, c = tid >> 3;
  int s = 0; float f = 0.f;
  for (int b = c * 64; b < c * 64 + 64; ++b){
    s += partial_hist[b * 8 + e]; f += partial_probs[b * 8 + e];
  }
  csum[c][e] = s; cps[c][e] = f;
  __syncthreads();
  if (tid < 8){
    int tot = 0;
    for (int cc = 0; cc < 8; ++cc){ cbase[cc][tid] = tot; tot += csum[cc][tid]; }
    csum[0][tid] = tot;            // column total (cbase already captured)
  }
  __syncthreads();
  if (tid == 0){
    int off = 0;
    for (int ee = 0; ee < 8; ++ee){ base_s[ee] = off; off += (csum[0][ee] + 255) & ~255; }
    meta[0] = off;                 // padded total (256-aligned)
    float a = 0.f;
    for (int ee = 0; ee < 8; ++ee){
      float ps = 0.f;
      for (int cc = 0; cc < 8; ++cc) ps += cps[cc][ee];
      float m = ps * (1.f / (float)T);
      a += m * m;
    }
    out_aux[0] = (float)E * a;
  }
  __syncthreads();
  int run = base_s[e] + cbase[c][e];
  for (int b = c * 64; b < c * 64 + 64; ++b){
    block_offset[b * 8 + e] = run;
    run += partial_hist[b * 8 + e];
  }
}

// ---------------- scatter: ballot-ranked, atomic-free ------------------------
__global__ void __launch_bounds__(64) scatter_kernel(
    const int* __restrict__ topk_idx, const float* __restrict__ topk_w,
    const int* __restrict__ block_offset,
    int* __restrict__ pair_token, int* __restrict__ pair_expert,
    float* __restrict__ pair_score, int* __restrict__ token_pos)
{
  int lane = threadIdx.x, b = blockIdx.x;
  if (lane >= 32) return;
  int idx = b * 32 + lane;
  int t = idx >> 1;
  int e = topk_idx[idx];
  float w = topk_w[idx];
  unsigned long long below = lane ? ((1ull << lane) - 1ull) : 0ull;
  int rank = 0, basee = 0;
#pragma unroll
  for (int ee = 0; ee < 8; ++ee){
    unsigned long long m = __ballot(e == ee);
    if (e == ee){ rank = __popcll(m & below); basee = block_offset[b * 8 + ee]; }
  }
  int pos = basee + rank;
  pair_token[pos] = t;
  pair_expert[pos] = e;
  pair_score[pos] = w;
  token_pos[idx] = pos;
}

// ---------------- all weight transposes in ONE launch ------------------------
// z: 0 Wsg->WsguT(lo), 1 Wsu->WsguT(hi), 2 Wsd->WsdT(plain),
//    [3,11) Wg->WguT(lo), [11,19) Wu->WguT(hi), [19,27) Wd->WdT(plain).
// Interleave: dst row for src col c: lo -> (c>>4)*32 + (c&15); hi -> +16.
// So B^T rows [32b,32b+16) = G cols [16b,16b+16), rows [32b+16,32b+32) = U.
__global__ void __launch_bounds__(256) transpose_all(
    const float* __restrict__ Wsg, const float* __restrict__ Wsu, u16* __restrict__ WsguT,
    const float* __restrict__ Wsd, u16* __restrict__ WsdT,
    const float* __restrict__ Wg,  const float* __restrict__ Wu, u16* __restrict__ WguT,
    const float* __restrict__ Wd,  u16* __restrict__ WdT)
{
  __shared__ float tile[32][33];
  int z = blockIdx.z;
  const float* src; u16* dst; int R, C, itype;
  if (z < 3){
    R = 1024; C = 1024;
    if (z == 0){ src = Wsg; dst = WsguT; itype = 1; }
    else if (z == 1){ src = Wsu; dst = WsguT; itype = 2; }
    else { src = Wsd; dst = WsdT; itype = 0; }
  } else if (z < 19){
    R = 1024; C = 512;
    int p = z - 3;
    if (p < 8){ src = Wg + (long)p * R * C; dst = WguT + (long)p * (2 * D * H); itype = 1; }
    else      { src = Wu + (long)(p - 8) * R * C; dst = WguT + (long)(p - 8) * (2 * D * H); itype = 2; }
  } else {
    R = 512; C = 1024;
    int p = z - 19;
    src = Wd + (long)p * R * C; dst = WdT + (long)p * R * C; itype = 0;
  }
  int tx = threadIdx.x & 31, ty = threadIdx.x >> 5;
  int c = blockIdx.x * 32 + tx;
  int rb = blockIdx.y * 32;
  if (blockIdx.x * 32 >= C || rb >= R) return;
#pragma unroll
  for (int j = 0; j < 4; ++j)
    tile[ty + j * 8][tx] = src[(long)(rb + ty + j * 8) * C + c];
  __syncthreads();
#pragma unroll
  for (int j = 0; j < 4; ++j){
    int cc = blockIdx.x * 32 + ty + j * 8;
    int dr = (itype == 0) ? cc : ((cc >> 4) * 32 + (cc & 15) + ((itype == 2) ? 16 : 0));
    dst[(long)dr * R + rb + tx] = f2bf(tile[tx][ty + j * 8]);
  }
}

// ---------------- 256x256x64, 8-wave, 8-phase GEMM template ------------------
// Per-wave 128x64 output (wm in 2, wn in 4). LDS: A[2buf][2half][128][64] +
// B same = 128 KiB. Stage schedule per K-tile t (4 quadrant phases qd):
//   qd0: stage A-half0(t+1)   qd1: stage A-half1(t+1)
//   qd2: stage B-half0(t+2)   qd3: stage B-half1(t+2), then vmcnt(4)
// Invariants: slot's new stage issued >=1 barrier after its last read;
// vmcnt(4)+barrier at group end leaves only B(t+2)'s 4 loads outstanding, so
// A(t+1)/B(t+1) are landed before group t+1 reads them.
struct HalfStage { const u16* p[2]; };

__device__ __forceinline__ void half_init(HalfStage& hs, const u16* __restrict__ gbase,
    int ld, int rowbase, const int* __restrict__ gather, int wave, int lane){
  int lr = lane >> 3, ch = lane & 7;
  int chs = (ch ^ lr) * 8;         // swizzled source chunk (LDS stays linear)
#pragma unroll
  for (int j = 0; j < 2; ++j){
    int row = (wave * 2 + j) * 8 + lr;          // 0..127
    int grow = gather ? gather[rowbase + row] : (rowbase + row);
    hs.p[j] = gbase + (long)grow * ld + chs;
  }
}

__device__ __forceinline__ void half_issue(const HalfStage& hs, int k0,
                                           u16* __restrict__ lds, int wave){
#pragma unroll
  for (int j = 0; j < 2; ++j)
    gl_lds16(hs.p[j] + k0, lds + (wave * 2 + j) * 512);
}

// EPI: 0 = gateup (interleaved G/U, SwiGLU -> bf16 o_bf, ld o_ld)
//      1 = down_routed (scale by pair_score -> bf16 rout)
//      2 = down_shared (+ combine via token_pos -> fp32 out)
template<int EPI>
__device__ __forceinline__ void gemm256(
    const u16* __restrict__ A, const u16* __restrict__ B, int K, int NT,
    const int* __restrict__ gather, int m0, int n0,
    u16* __restrict__ o_bf, int o_ld,
    const float* __restrict__ pair_score,
    const int* __restrict__ token_pos, const u16* __restrict__ rout,
    float* __restrict__ out,
    u16* __restrict__ As, u16* __restrict__ Bs)
{
  int tid = threadIdx.x, lane = tid & 63, wave = tid >> 6;
  int wm = wave >> 2, wn = wave & 3;
  int rl = lane & 15, q = lane >> 4;

  HalfStage a0, a1, b0, b1;
  half_init(a0, A, K, m0,       gather, wave, lane);
  half_init(a1, A, K, m0 + 128, gather, wave, lane);
  half_init(b0, B, K, n0,       nullptr, wave, lane);
  half_init(b1, B, K, n0 + 128, nullptr, wave, lane);

  f32x4 acc[8][4];
#pragma unroll
  for (int i = 0; i < 8; ++i)
#pragma unroll
    for (int j = 0; j < 4; ++j)
#pragma unroll
      for (int r = 0; r < 4; ++r) acc[i][j][r] = 0.f;

  // prologue: tile0 fully + tile1 B halves; vmcnt(4) -> tile0 landed
  half_issue(b0, 0, Bs + 0 * 8192, wave);
  half_issue(b1, 0, Bs + 1 * 8192, wave);
  half_issue(a0, 0, As + 0 * 8192, wave);
  half_issue(a1, 0, As + 1 * 8192, wave);
  if (NT > 1){
    half_issue(b0, 64, Bs + 2 * 8192, wave);
    half_issue(b1, 64, Bs + 3 * 8192, wave);
    wait_vmcnt4();
  } else {
    wait_vmcnt0();
  }
  bar_sync();

  int bhalf = wn >> 1, brow0 = (wn & 1) * 64;

#pragma unroll 1
  for (int t = 0; t < NT; ++t){
    int buf = t & 1, nbuf = buf ^ 1;
    const u16* Abase = As + (buf * 2 + wm) * 8192;
    const u16* Bbase = Bs + (buf * 2 + bhalf) * 8192;
    short8 bfr[2][4];
#pragma unroll
    for (int qd = 0; qd < 4; ++qd){
      // 1. ds-reads: A quadrant (4x b128); + all B frags (8x b128) at qd==0
      short8 afr[2][2];
#pragma unroll
      for (int ks = 0; ks < 2; ++ks){
        int off = swz_off(ks * 4 + q, lane);
#pragma unroll
        for (int m = 0; m < 2; ++m)
          afr[ks][m] = *(const short8*)(Abase + (qd * 32 + m * 16 + rl) * 64 + off);
        if (qd == 0){
#pragma unroll
          for (int n = 0; n < 4; ++n)
            bfr[ks][n] = *(const short8*)(Bbase + (brow0 + n * 16 + rl) * 64 + off);
        }
      }
      // 2. stage-issue per schedule
      if (qd == 0 && t + 1 < NT) half_issue(a0, (t + 1) * 64, As + (nbuf * 2 + 0) * 8192, wave);
      if (qd == 1 && t + 1 < NT) half_issue(a1, (t + 1) * 64, As + (nbuf * 2 + 1) * 8192, wave);
      if (qd == 2 && t + 2 < NT) half_issue(b0, (t + 2) * 64, Bs + (buf * 2 + 0) * 8192, wave);
      if (qd == 3 && t + 2 < NT) half_issue(b1, (t + 2) * 64, Bs + (buf * 2 + 1) * 8192, wave);
      // 3. barrier; compiler inserts lgkm waits before MFMA use
      bar_sync();
      // 4. MFMA cluster (16), T5 setprio
      __builtin_amdgcn_s_setprio(1);
#pragma unroll
      for (int ks = 0; ks < 2; ++ks)
#pragma unroll
        for (int m = 0; m < 2; ++m)
#pragma unroll
          for (int n = 0; n < 4; ++n)
            acc[qd * 2 + m][n] = __builtin_amdgcn_mfma_f32_16x16x32_bf16(
                afr[ks][m], bfr[ks][n], acc[qd * 2 + m][n], 0, 0, 0);
      __builtin_amdgcn_s_setprio(0);
      // 5. counted vmcnt once per K-tile, then end-of-phase barrier
      if (qd == 3) wait_vmcnt4();
      bar_sync();
    }
  }

  int row0 = m0 + wm * 128;
  if constexpr (EPI == 0){
    int hcol0 = (n0 >> 1) + wn * 32;
#pragma unroll
    for (int mt = 0; mt < 8; ++mt)
#pragma unroll
      for (int ntp = 0; ntp < 2; ++ntp)
#pragma unroll
        for (int r = 0; r < 4; ++r){
          int row = row0 + mt * 16 + q * 4 + r;
          int col = hcol0 + ntp * 16 + rl;
          float g = acc[mt][2 * ntp][r], u = acc[mt][2 * ntp + 1][r];
          float h = g / (1.f + __expf(-g)) * u;
          o_bf[(long)row * o_ld + col] = f2bf(h);
        }
  } else if constexpr (EPI == 1){
    int col0 = n0 + wn * 64;
#pragma unroll
    for (int mt = 0; mt < 8; ++mt)
#pragma unroll
      for (int r = 0; r < 4; ++r){
        int row = row0 + mt * 16 + q * 4 + r;
        float s = pair_score[row];
        long rbase = (long)row * H;
#pragma unroll
        for (int n = 0; n < 4; ++n){
          int col = col0 + n * 16 + rl;
          o_bf[rbase + col] = f2bf(s * acc[mt][n][r]);
        }
      }
  } else {
    int col0 = n0 + wn * 64;
#pragma unroll
    for (int mt = 0; mt < 8; ++mt)
#pragma unroll
      for (int r = 0; r < 4; ++r){
        int row = row0 + mt * 16 + q * 4 + r;
        int p0 = token_pos[2 * row], p1 = token_pos[2 * row + 1];
        long o = (long)row * H;
#pragma unroll
        for (int n = 0; n < 4; ++n){
          int col = col0 + n * 16 + rl;
          out[o + col] = acc[mt][n][r]
                       + bf2f(rout[(long)p0 * H + col])
                       + bf2f(rout[(long)p1 * H + col]);
        }
      }
  }
}

// ---------------- GEMM kernels ----------------------------------------------
__global__ void __launch_bounds__(512, 2) gateup_fused(
    const u16* __restrict__ xb, const u16* __restrict__ WguT, u16* __restrict__ hr,
    const u16* __restrict__ WsguT, u16* __restrict__ hs,
    const int* __restrict__ pair_token, const int* __restrict__ pair_expert,
    const int* __restrict__ meta)
{
  __shared__ u16 As[4 * 8192];
  __shared__ u16 Bs[4 * 8192];
  int fid = blockIdx.x;
  if (fid < GU_ROUTED_BLKS){
    int x8 = fid & 7, s = fid >> 3;                // s in [0,36)
    int mtile = x8 + 8 * (s >> 2), ntile = s & 3;
    int m0 = mtile * 256;
    if (m0 >= meta[0]) return;                     // all-dummy tile
    int e = pair_expert[m0];
    gemm256<0>(xb, WguT + (long)e * (2 * D * H), H, H / 64, pair_token,
               m0, ntile * 256, hr, D, nullptr, nullptr, nullptr, nullptr, As, Bs);
  } else {
    int lid = fid - GU_ROUTED_BLKS;
    int x8 = lid & 7, s = lid >> 3;                // s in [0,32)
    int mtile = x8 + 8 * (s >> 3), ntile = s & 7;
    gemm256<0>(xb, WsguT, H, H / 64, nullptr,
               mtile * 256, ntile * 256, hs, DS, nullptr, nullptr, nullptr, nullptr, As, Bs);
  }
}

__global__ void __launch_bounds__(512, 2) down_routed_kernel(
    const u16* __restrict__ hr, const u16* __restrict__ WdT, u16* __restrict__ rout,
    const float* __restrict__ pair_score, const int* __restrict__ pair_expert,
    const int* __restrict__ meta)
{
  __shared__ u16 As[4 * 8192];
  __shared__ u16 Bs[4 * 8192];
  int fid = blockIdx.x;
  int x8 = fid & 7, s = fid >> 3;                  // s in [0,36)
  int mtile = x8 + 8 * (s >> 2), ntile = s & 3;
  int m0 = mtile * 256;
  if (m0 >= meta[0]) return;
  int e = pair_expert[m0];
  gemm256<1>(hr, WdT + (long)e * (H * D), D, D / 64, nullptr,
             m0, ntile * 256, rout, H, pair_score, nullptr, nullptr, nullptr, As, Bs);
}

__global__ void __launch_bounds__(512, 2) down_shared_kernel(
    const u16* __restrict__ hs, const u16* __restrict__ WsdT,
    const u16* __restrict__ rout, const int* __restrict__ token_pos,
    float* __restrict__ out)
{
  __shared__ u16 As[4 * 8192];
  __shared__ u16 Bs[4 * 8192];
  int fid = blockIdx.x;
  int x8 = fid & 7, s = fid >> 3;                  // s in [0,16)
  int mtile = x8 + 8 * (s >> 2), ntile = s & 3;
  gemm256<2>(hs, WsdT, DS, DS / 64, nullptr,
             mtile * 256, ntile * 256, nullptr, 0, nullptr, token_pos, rout, out, As, Bs);
}

// ---------------- launch -----------------------------------------------------
extern "C" void kernel_launch(void* const* d_in, const int* in_sizes, int n_in,
                              void* d_out, int out_size, void* d_ws, size_t ws_size,
                              hipStream_t stream)
{
  (void)in_sizes; (void)n_in; (void)out_size; (void)ws_size;
  const float* x   = (const float*)d_in[0];
  const float* Wr  = (const float*)d_in[1];
  const float* Wg  = (const float*)d_in[2];
  const float* Wu  = (const float*)d_in[3];
  const float* Wd  = (const float*)d_in[4];
  const float* Wsg = (const float*)d_in[5];
  const float* Wsu = (const float*)d_in[6];
  const float* Wsd = (const float*)d_in[7];
  float* out = (float*)d_out;

  char* ws = (char*)d_ws;
  size_t off = 0;
  auto alloc = [&](size_t bytes) -> void* {
    void* p = ws + off; off += (bytes + 255) & ~(size_t)255; return p;
  };
  u16* xb    = (u16*)alloc((size_t)T * H * 2);
  u16* WsguT = (u16*)alloc((size_t)2 * DS * H * 2);   // [2048][1024] interleaved
  u16* WsdT  = (u16*)alloc((size_t)H * DS * 2);
  u16* WguT  = (u16*)alloc((size_t)E * 2 * D * H * 2); // per-e [1024][1024] interleaved
  u16* WdT   = (u16*)alloc((size_t)E * H * D * 2);
  u16* hs    = (u16*)alloc((size_t)T * DS * 2);
  u16* hr    = (u16*)alloc((size_t)PAIR_CAP * D * 2);
  u16* rout  = (u16*)alloc((size_t)PAIR_CAP * H * 2);
  int*   topk_idx  = (int*)alloc((size_t)T * 2 * 4);
  float* topk_w    = (float*)alloc((size_t)T * 2 * 4);
  int*   token_pos = (int*)alloc((size_t)T * 2 * 4);
  int*   partial_hist  = (int*)alloc((size_t)RB * 8 * 4);
  float* partial_probs = (float*)alloc((size_t)RB * 8 * 4);
  int*   block_offset  = (int*)alloc((size_t)RB * 8 * 4);
  int*   meta          = (int*)alloc(256);
  // zero-initialized region (dummy pair slots must read as 0)
  char* zbase = ws + off;
  int*   pair_token  = (int*)alloc((size_t)PAIR_CAP * 4);
  int*   pair_expert = (int*)alloc((size_t)PAIR_CAP * 4);
  float* pair_score  = (float*)alloc((size_t)PAIR_CAP * 4);
  size_t zbytes = (size_t)((ws + off) - zbase);

  hipMemsetAsync(zbase, 0, zbytes, stream);

  transpose_all<<<dim3(32, 32, 27), 256, 0, stream>>>(
      Wsg, Wsu, WsguT, Wsd, WsdT, Wg, Wu, WguT, Wd, WdT);

  router_kernel<<<RB, 256, 0, stream>>>(x, Wr, xb, topk_idx, topk_w,
                                        partial_hist, partial_probs);
  scan_kernel<<<1, 64, 0, stream>>>(partial_hist, partial_probs, block_offset,
                                    out + (size_t)T * H, meta);
  scatter_kernel<<<RB, 64, 0, stream>>>(topk_idx, topk_w, block_offset,
                                        pair_token, pair_expert, pair_score, token_pos);

  // fused gate+up (interleaved G/U): routed -> hr, shared -> hs
  gateup_fused<<<GU_ROUTED_BLKS + GU_SHARED_BLKS, 512, 0, stream>>>(
      xb, WguT, hr, WsguT, hs, pair_token, pair_expert, meta);

  // routed down -> rout [PAIR_CAP x H], scaled by pair score
  down_routed_kernel<<<DR_BLKS, 512, 0, stream>>>(
      hr, WdT, rout, pair_score, pair_expert, meta);
  // shared down + combine -> out [T x H] fp32
  down_shared_kernel<<<DSH_BLKS, 512, 0, stream>>>(
      hs, WsdT, rout, token_pos, out);
}

// Round 2
// 363.980 us; speedup vs baseline: 1.1573x; 1.1573x over previous
//
#include <hip/hip_runtime.h>

// MoE forward: shared SwiGLU expert + top-2/8 routed SwiGLU experts + aux loss.
// R8: 256x256x64 8-wave 8-phase template with RAW s_barrier + sched_barrier(0)
// pins (no fences -> counted vmcnt(4) pipeline actually live; R7's fences
// forced vmcnt(0) drains at every barrier, collapsing the pipeline to the
// ~26% m97 ceiling). Tail fix: vmcnt(0) at tile NT-2 (steady-state vmcnt(4)
// would leave A(NT-1) halves undrained -> race without the fence drain).
// Wg/Wu interleaved (16-col blocks) into WguT so gate+up is ONE GEMM with
// SwiGLU fused in epilogue. Routed pad 256, meta early-exit. XOR chunk swizzle.

typedef unsigned short u16;
typedef unsigned int   u32;
typedef short short8 __attribute__((ext_vector_type(8)));
typedef float f32x4  __attribute__((ext_vector_type(4)));

#define AS1 __attribute__((address_space(1)))
#define AS3 __attribute__((address_space(3)))

constexpr int T  = 8192;
constexpr int H  = 1024;
constexpr int E  = 8;
constexpr int D  = 512;
constexpr int DS = 1024;          // shared expert width
constexpr int PAIR_CAP  = 18432;  // 72*256 >= 16384 + 8*255, 256-aligned
constexpr int MT_ROUTED = 72;     // routed m-tiles (256 rows each)
constexpr int RB = 512;           // router blocks (16 tokens each)

constexpr int GU_ROUTED_BLKS = 4 * MT_ROUTED;   // 288 (N=1024 interleaved -> 4 ntiles)
constexpr int GU_SHARED_BLKS = 8 * (T / 256);   // 256 (N=2048 interleaved -> 8 ntiles)
constexpr int DR_BLKS = 4 * MT_ROUTED;          // 288 (N=1024 -> 4 ntiles)
constexpr int DSH_BLKS = 4 * (T / 256);         // 128 (N=1024 -> 4 ntiles)

__device__ __forceinline__ u16 f2bf(float f){
  u32 u = __builtin_bit_cast(u32, f);
  u += 0x7fffu + ((u >> 16) & 1u);   // round-to-nearest-even
  return (u16)(u >> 16);
}
__device__ __forceinline__ float bf2f(u16 h){
  u32 u = ((u32)h) << 16;
  return __builtin_bit_cast(float, u);
}

// async global->LDS, 16B per lane. LDS dest = wave-uniform base + lane*16.
__device__ __forceinline__ void gl_lds16(const u16* g, u16* l){
  __builtin_amdgcn_global_load_lds((const AS1 void*)g, (AS3 void*)l, 16, 0, 0);
}

// s_waitcnt imm: vm[3:0] | exp=7<<4 | lgkm=15<<8
__device__ __forceinline__ void wait_vmcnt4(){ __builtin_amdgcn_s_waitcnt(0x0f74); }
__device__ __forceinline__ void wait_vmcnt0(){ __builtin_amdgcn_s_waitcnt(0x0f70); }

// RAW workgroup barrier + scheduling pin. No fence: vmcnt stays counted
// (correctness of LDS data is carried by the counted vmcnt discipline), and
// sched_barrier(0) stops the compiler moving plain ds_reads / MFMAs across
// the barrier (they are not ordered vs intrinsics otherwise).
__device__ __forceinline__ void bar(){
  __builtin_amdgcn_s_barrier();
  __builtin_amdgcn_sched_barrier(0);
}

// Fragment read offset (elems) for logical chunk c at a row with row&7==lane&7.
__device__ __forceinline__ int swz_off(int c, int lane){
  return ((c ^ (lane & 7)) * 8);
}

// ---------------- router: logits -> softmax -> top2 + bf16 convert of x -----
__global__ void __launch_bounds__(256) router_kernel(
    const float* __restrict__ x, const float* __restrict__ Wr,
    u16* __restrict__ xb,
    int* __restrict__ topk_idx, float* __restrict__ topk_w,
    int* __restrict__ partial_hist, float* __restrict__ partial_probs)
{
  __shared__ int   hist_s[4][8];
  __shared__ float ps_s[4][8];
  int tid = threadIdx.x, lane = tid & 63, wv = tid >> 6;
  int   histl[8] = {0,0,0,0,0,0,0,0};
  float psl[8]   = {0.f,0.f,0.f,0.f,0.f,0.f,0.f,0.f};

  for (int it = 0; it < 4; ++it){
    int t = blockIdx.x * 16 + wv * 4 + it;
    const float4* xr = (const float4*)(x + (long)t * H);
    uint2* xbr = (uint2*)(xb + (long)t * H);
    float acc[8];
#pragma unroll
    for (int e = 0; e < 8; ++e) acc[e] = 0.f;
#pragma unroll
    for (int i = 0; i < 4; ++i){
      float4 xv = xr[i * 64 + lane];
      u32 lo = (u32)f2bf(xv.x) | ((u32)f2bf(xv.y) << 16);
      u32 hi = (u32)f2bf(xv.z) | ((u32)f2bf(xv.w) << 16);
      xbr[i * 64 + lane] = make_uint2(lo, hi);
      int h0 = i * 256 + lane * 4;
#pragma unroll
      for (int j = 0; j < 4; ++j){
        float xs = (j == 0) ? xv.x : (j == 1) ? xv.y : (j == 2) ? xv.z : xv.w;
        const float4* wr = (const float4*)(Wr + (long)(h0 + j) * E);
        float4 w0 = wr[0], w1 = wr[1];
        acc[0] += xs * w0.x; acc[1] += xs * w0.y; acc[2] += xs * w0.z; acc[3] += xs * w0.w;
        acc[4] += xs * w1.x; acc[5] += xs * w1.y; acc[6] += xs * w1.z; acc[7] += xs * w1.w;
      }
    }
#pragma unroll
    for (int off = 32; off >= 1; off >>= 1){
#pragma unroll
      for (int e = 0; e < 8; ++e) acc[e] += __shfl_xor(acc[e], off, 64);
    }
    if (lane == 0){
      float m = acc[0];
#pragma unroll
      for (int e = 1; e < 8; ++e) m = fmaxf(m, acc[e]);
      float p[8], s = 0.f;
#pragma unroll
      for (int e = 0; e < 8; ++e){ p[e] = __expf(acc[e] - m); s += p[e]; }
      float inv = 1.f / s;
#pragma unroll
      for (int e = 0; e < 8; ++e) psl[e] += p[e] * inv;
      int i1 = 0; float v1 = p[0];
#pragma unroll
      for (int e = 1; e < 8; ++e) if (p[e] > v1){ v1 = p[e]; i1 = e; }
      int i2 = -1; float v2 = -1.f;
#pragma unroll
      for (int e = 0; e < 8; ++e) if (e != i1 && p[e] > v2){ v2 = p[e]; i2 = e; }
      float rs = 1.f / (v1 + v2);
      topk_idx[2 * t] = i1; topk_idx[2 * t + 1] = i2;
      topk_w[2 * t] = v1 * rs; topk_w[2 * t + 1] = v2 * rs;
      histl[i1]++; histl[i2]++;
    }
  }
  if (lane == 0){
#pragma unroll
    for (int e = 0; e < 8; ++e){ hist_s[wv][e] = histl[e]; ps_s[wv][e] = psl[e]; }
  }
  __syncthreads();
  if (tid < 8){
    int hs = 0; float ps = 0.f;
#pragma unroll
    for (int w = 0; w < 4; ++w){ hs += hist_s[w][tid]; ps += ps_s[w][tid]; }
    partial_hist[blockIdx.x * 8 + tid]  = hs;
    partial_probs[blockIdx.x * 8 + tid] = ps;
  }
}

// ---------------- scan: 256-padded bases + per-block offsets + aux loss ------
__global__ void __launch_bounds__(64) scan_kernel(
    const int* __restrict__ partial_hist, const float* __restrict__ partial_probs,
    int* __restrict__ block_offset, float* __restrict__ out_aux,
    int* __restrict__ meta)
{
  __shared__ int   csum[8][8];
  __shared__ float cps[8][8];
  __shared__ int   cbase[8][8];
  __shared__ int   base_s[8];
  int tid = threadIdx.x, e = tid & 7, c = tid >> 3;
  int s = 0; float f = 0.f;
  for (int b = c * 64; b < c * 64 + 64; ++b){
    s += partial_hist[b * 8 + e]; f += partial_probs[b * 8 + e];
  }
  csum[c][e] = s; cps[c][e] = f;
  __syncthreads();
  if (tid < 8){
    int tot = 0;
    for (int cc = 0; cc < 8; ++cc){ cbase[cc][tid] = tot; tot += csum[cc][tid]; }
    csum[0][tid] = tot;            // column total (cbase already captured)
  }
  __syncthreads();
  if (tid == 0){
    int off = 0;
    for (int ee = 0; ee < 8; ++ee){ base_s[ee] = off; off += (csum[0][ee] + 255) & ~255; }
    meta[0] = off;                 // padded total (256-aligned)
    float a = 0.f;
    for (int ee = 0; ee < 8; ++ee){
      float ps = 0.f;
      for (int cc = 0; cc < 8; ++cc) ps += cps[cc][ee];
      float m = ps * (1.f / (float)T);
      a += m * m;
    }
    out_aux[0] = (float)E * a;
  }
  __syncthreads();
  int run = base_s[e] + cbase[c][e];
  for (int b = c * 64; b < c * 64 + 64; ++b){
    block_offset[b * 8 + e] = run;
    run += partial_hist[b * 8 + e];
  }
}

// ---------------- scatter: ballot-ranked, atomic-free ------------------------
__global__ void __launch_bounds__(64) scatter_kernel(
    const int* __restrict__ topk_idx, const float* __restrict__ topk_w,
    const int* __restrict__ block_offset,
    int* __restrict__ pair_token, int* __restrict__ pair_expert,
    float* __restrict__ pair_score, int* __restrict__ token_pos)
{
  int lane = threadIdx.x, b = blockIdx.x;
  if (lane >= 32) return;
  int idx = b * 32 + lane;
  int t = idx >> 1;
  int e = topk_idx[idx];
  float w = topk_w[idx];
  unsigned long long below = lane ? ((1ull << lane) - 1ull) : 0ull;
  int rank = 0, basee = 0;
#pragma unroll
  for (int ee = 0; ee < 8; ++ee){
    unsigned long long m = __ballot(e == ee);
    if (e == ee){ rank = __popcll(m & below); basee = block_offset[b * 8 + ee]; }
  }
  int pos = basee + rank;
  pair_token[pos] = t;
  pair_expert[pos] = e;
  pair_score[pos] = w;
  token_pos[idx] = pos;
}

// ---------------- all weight transposes in ONE launch ------------------------
// z: 0 Wsg->WsguT(lo), 1 Wsu->WsguT(hi), 2 Wsd->WsdT(plain),
//    [3,11) Wg->WguT(lo), [11,19) Wu->WguT(hi), [19,27) Wd->WdT(plain).
// Interleave: dst row for src col c: lo -> (c>>4)*32 + (c&15); hi -> +16.
__global__ void __launch_bounds__(256) transpose_all(
    const float* __restrict__ Wsg, const float* __restrict__ Wsu, u16* __restrict__ WsguT,
    const float* __restrict__ Wsd, u16* __restrict__ WsdT,
    const float* __restrict__ Wg,  const float* __restrict__ Wu, u16* __restrict__ WguT,
    const float* __restrict__ Wd,  u16* __restrict__ WdT)
{
  __shared__ float tile[32][33];
  int z = blockIdx.z;
  const float* src; u16* dst; int R, C, itype;
  if (z < 3){
    R = 1024; C = 1024;
    if (z == 0){ src = Wsg; dst = WsguT; itype = 1; }
    else if (z == 1){ src = Wsu; dst = WsguT; itype = 2; }
    else { src = Wsd; dst = WsdT; itype = 0; }
  } else if (z < 19){
    R = 1024; C = 512;
    int p = z - 3;
    if (p < 8){ src = Wg + (long)p * R * C; dst = WguT + (long)p * (2 * D * H); itype = 1; }
    else      { src = Wu + (long)(p - 8) * R * C; dst = WguT + (long)(p - 8) * (2 * D * H); itype = 2; }
  } else {
    R = 512; C = 1024;
    int p = z - 19;
    src = Wd + (long)p * R * C; dst = WdT + (long)p * R * C; itype = 0;
  }
  int tx = threadIdx.x & 31, ty = threadIdx.x >> 5;
  int c = blockIdx.x * 32 + tx;
  int rb = blockIdx.y * 32;
  if (blockIdx.x * 32 >= C || rb >= R) return;
#pragma unroll
  for (int j = 0; j < 4; ++j)
    tile[ty + j * 8][tx] = src[(long)(rb + ty + j * 8) * C + c];
  __syncthreads();
#pragma unroll
  for (int j = 0; j < 4; ++j){
    int cc = blockIdx.x * 32 + ty + j * 8;
    int dr = (itype == 0) ? cc : ((cc >> 4) * 32 + (cc & 15) + ((itype == 2) ? 16 : 0));
    dst[(long)dr * R + rb + tx] = f2bf(tile[tx][ty + j * 8]);
  }
}

// ---------------- 256x256x64, 8-wave, 8-phase GEMM template ------------------
// Per-wave 128x64 output (wm in 2, wn in 4). LDS: A[2buf][2half][128][64] +
// B same = 128 KiB. Stage schedule per K-tile t (4 quadrant phases qd):
//   qd0: stage A-half0(t+1)   qd1: stage A-half1(t+1)
//   qd2: stage B-half0(t+2)   qd3: stage B-half1(t+2), then vmcnt(4)
// Steady state at t/qd3: outstanding (oldest first) B0(t+1),B1(t+1),A0(t+1),
// A1(t+1),B0(t+2),B1(t+2) = 12 lane-loads; vmcnt(4) drains through A1(t+1),
// leaving only B(t+2) in flight -> tile t+1's operands landed before its
// first read. TAIL: at t = NT-2 no B(t+2) is issued (8 outstanding), so
// vmcnt(4) would leave A(NT-1) undrained -> must use vmcnt(0) there.
struct HalfStage { const u16* p[2]; };

__device__ __forceinline__ void half_init(HalfStage& hs, const u16* __restrict__ gbase,
    int ld, int rowbase, const int* __restrict__ gather, int wave, int lane){
  int lr = lane >> 3, ch = lane & 7;
  int chs = (ch ^ lr) * 8;         // swizzled source chunk (LDS stays linear)
#pragma unroll
  for (int j = 0; j < 2; ++j){
    int row = (wave * 2 + j) * 8 + lr;          // 0..127
    int grow = gather ? gather[rowbase + row] : (rowbase + row);
    hs.p[j] = gbase + (long)grow * ld + chs;
  }
}

__device__ __forceinline__ void half_issue(const HalfStage& hs, int k0,
                                           u16* __restrict__ lds, int wave){
#pragma unroll
  for (int j = 0; j < 2; ++j)
    gl_lds16(hs.p[j] + k0, lds + (wave * 2 + j) * 512);
}

// EPI: 0 = gateup (interleaved G/U, SwiGLU -> bf16 o_bf, ld o_ld)
//      1 = down_routed (scale by pair_score -> bf16 rout)
//      2 = down_shared (+ combine via token_pos -> fp32 out)
template<int EPI>
__device__ __forceinline__ void gemm256(
    const u16* __restrict__ A, const u16* __restrict__ B, int K, int NT,
    const int* __restrict__ gather, int m0, int n0,
    u16* __restrict__ o_bf, int o_ld,
    const float* __restrict__ pair_score,
    const int* __restrict__ token_pos, const u16* __restrict__ rout,
    float* __restrict__ out,
    u16* __restrict__ As, u16* __restrict__ Bs)
{
  int tid = threadIdx.x, lane = tid & 63, wave = tid >> 6;
  int wm = wave >> 2, wn = wave & 3;
  int rl = lane & 15, q = lane >> 4;

  HalfStage a0, a1, b0, b1;
  half_init(a0, A, K, m0,       gather, wave, lane);
  half_init(a1, A, K, m0 + 128, gather, wave, lane);
  half_init(b0, B, K, n0,       nullptr, wave, lane);
  half_init(b1, B, K, n0 + 128, nullptr, wave, lane);

  f32x4 acc[8][4];
#pragma unroll
  for (int i = 0; i < 8; ++i)
#pragma unroll
    for (int j = 0; j < 4; ++j)
#pragma unroll
      for (int r = 0; r < 4; ++r) acc[i][j][r] = 0.f;

  // prologue: tile0 fully + tile1 B halves; vmcnt(4) -> tile0 landed
  half_issue(b0, 0, Bs + 0 * 8192, wave);
  half_issue(b1, 0, Bs + 1 * 8192, wave);
  half_issue(a0, 0, As + 0 * 8192, wave);
  half_issue(a1, 0, As + 1 * 8192, wave);
  if (NT > 1){
    half_issue(b0, 64, Bs + 2 * 8192, wave);
    half_issue(b1, 64, Bs + 3 * 8192, wave);
    wait_vmcnt4();
  } else {
    wait_vmcnt0();
  }
  bar();

  int bhalf = wn >> 1, brow0 = (wn & 1) * 64;

#pragma unroll 1
  for (int t = 0; t < NT; ++t){
    int buf = t & 1, nbuf = buf ^ 1;
    const u16* Abase = As + (buf * 2 + wm) * 8192;
    const u16* Bbase = Bs + (buf * 2 + bhalf) * 8192;
    short8 bfr[2][4];
#pragma unroll
    for (int qd = 0; qd < 4; ++qd){
      // 1. ds-reads: A quadrant (4x b128); + all B frags (8x b128) at qd==0
      short8 afr[2][2];
#pragma unroll
      for (int ks = 0; ks < 2; ++ks){
        int off = swz_off(ks * 4 + q, lane);
#pragma unroll
        for (int m = 0; m < 2; ++m)
          afr[ks][m] = *(const short8*)(Abase + (qd * 32 + m * 16 + rl) * 64 + off);
        if (qd == 0){
#pragma unroll
          for (int n = 0; n < 4; ++n)
            bfr[ks][n] = *(const short8*)(Bbase + (brow0 + n * 16 + rl) * 64 + off);
        }
      }
      // 2. stage-issue per schedule
      if (qd == 0 && t + 1 < NT) half_issue(a0, (t + 1) * 64, As + (nbuf * 2 + 0) * 8192, wave);
      if (qd == 1 && t + 1 < NT) half_issue(a1, (t + 1) * 64, As + (nbuf * 2 + 1) * 8192, wave);
      if (qd == 2 && t + 2 < NT) half_issue(b0, (t + 2) * 64, Bs + (buf * 2 + 0) * 8192, wave);
      if (qd == 3 && t + 2 < NT) half_issue(b1, (t + 2) * 64, Bs + (buf * 2 + 1) * 8192, wave);
      // 3. raw barrier + pin; compiler inserts fine-grained lgkm waits for the
      //    ds_read results before their MFMA uses.
      bar();
      // 4. MFMA cluster (16), T5 setprio
      __builtin_amdgcn_s_setprio(1);
#pragma unroll
      for (int ks = 0; ks < 2; ++ks)
#pragma unroll
        for (int m = 0; m < 2; ++m)
#pragma unroll
          for (int n = 0; n < 4; ++n)
            acc[qd * 2 + m][n] = __builtin_amdgcn_mfma_f32_16x16x32_bf16(
                afr[ks][m], bfr[ks][n], acc[qd * 2 + m][n], 0, 0, 0);
      __builtin_amdgcn_s_setprio(0);
      // 5. counted vmcnt once per K-tile (tail: full drain at NT-2/NT-1)
      if (qd == 3){
        if (t + 2 < NT) wait_vmcnt4(); else wait_vmcnt0();
      }
      bar();
    }
  }

  int row0 = m0 + wm * 128;
  if constexpr (EPI == 0){
    int hcol0 = (n0 >> 1) + wn * 32;
#pragma unroll
    for (int mt = 0; mt < 8; ++mt)
#pragma unroll
      for (int ntp = 0; ntp < 2; ++ntp)
#pragma unroll
        for (int r = 0; r < 4; ++r){
          int row = row0 + mt * 16 + q * 4 + r;
          int col = hcol0 + ntp * 16 + rl;
          float g = acc[mt][2 * ntp][r], u = acc[mt][2 * ntp + 1][r];
          float h = g / (1.f + __expf(-g)) * u;
          o_bf[(long)row * o_ld + col] = f2bf(h);
        }
  } else if constexpr (EPI == 1){
    int col0 = n0 + wn * 64;
#pragma unroll
    for (int mt = 0; mt < 8; ++mt)
#pragma unroll
      for (int r = 0; r < 4; ++r){
        int row = row0 + mt * 16 + q * 4 + r;
        float s = pair_score[row];
        long rbase = (long)row * H;
#pragma unroll
        for (int n = 0; n < 4; ++n){
          int col = col0 + n * 16 + rl;
          o_bf[rbase + col] = f2bf(s * acc[mt][n][r]);
        }
      }
  } else {
    int col0 = n0 + wn * 64;
#pragma unroll
    for (int mt = 0; mt < 8; ++mt)
#pragma unroll
      for (int r = 0; r < 4; ++r){
        int row = row0 + mt * 16 + q * 4 + r;
        int p0 = token_pos[2 * row], p1 = token_pos[2 * row + 1];
        long o = (long)row * H;
#pragma unroll
        for (int n = 0; n < 4; ++n){
          int col = col0 + n * 16 + rl;
          out[o + col] = acc[mt][n][r]
                       + bf2f(rout[(long)p0 * H + col])
                       + bf2f(rout[(long)p1 * H + col]);
        }
      }
  }
}

// ---------------- GEMM kernels ----------------------------------------------
__global__ void __launch_bounds__(512, 2) gateup_fused(
    const u16* __restrict__ xb, const u16* __restrict__ WguT, u16* __restrict__ hr,
    const u16* __restrict__ WsguT, u16* __restrict__ hs,
    const int* __restrict__ pair_token, const int* __restrict__ pair_expert,
    const int* __restrict__ meta)
{
  __shared__ u16 As[4 * 8192];
  __shared__ u16 Bs[4 * 8192];
  int fid = blockIdx.x;
  if (fid < GU_ROUTED_BLKS){
    int x8 = fid & 7, s = fid >> 3;                // s in [0,36)
    int mtile = x8 + 8 * (s >> 2), ntile = s & 3;
    int m0 = mtile * 256;
    if (m0 >= meta[0]) return;                     // all-dummy tile
    int e = pair_expert[m0];
    gemm256<0>(xb, WguT + (long)e * (2 * D * H), H, H / 64, pair_token,
               m0, ntile * 256, hr, D, nullptr, nullptr, nullptr, nullptr, As, Bs);
  } else {
    int lid = fid - GU_ROUTED_BLKS;
    int x8 = lid & 7, s = lid >> 3;                // s in [0,32)
    int mtile = x8 + 8 * (s >> 3), ntile = s & 7;
    gemm256<0>(xb, WsguT, H, H / 64, nullptr,
               mtile * 256, ntile * 256, hs, DS, nullptr, nullptr, nullptr, nullptr, As, Bs);
  }
}

__global__ void __launch_bounds__(512, 2) down_routed_kernel(
    const u16* __restrict__ hr, const u16* __restrict__ WdT, u16* __restrict__ rout,
    const float* __restrict__ pair_score, const int* __restrict__ pair_expert,
    const int* __restrict__ meta)
{
  __shared__ u16 As[4 * 8192];
  __shared__ u16 Bs[4 * 8192];
  int fid = blockIdx.x;
  int x8 = fid & 7, s = fid >> 3;                  // s in [0,36)
  int mtile = x8 + 8 * (s >> 2), ntile = s & 3;
  int m0 = mtile * 256;
  if (m0 >= meta[0]) return;
  int e = pair_expert[m0];
  gemm256<1>(hr, WdT + (long)e * (H * D), D, D / 64, nullptr,
             m0, ntile * 256, rout, H, pair_score, nullptr, nullptr, nullptr, As, Bs);
}

__global__ void __launch_bounds__(512, 2) down_shared_kernel(
    const u16* __restrict__ hs, const u16* __restrict__ WsdT,
    const u16* __restrict__ rout, const int* __restrict__ token_pos,
    float* __restrict__ out)
{
  __shared__ u16 As[4 * 8192];
  __shared__ u16 Bs[4 * 8192];
  int fid = blockIdx.x;
  int x8 = fid & 7, s = fid >> 3;                  // s in [0,16)
  int mtile = x8 + 8 * (s >> 2), ntile = s & 3;
  gemm256<2>(hs, WsdT, DS, DS / 64, nullptr,
             mtile * 256, ntile * 256, nullptr, 0, nullptr, token_pos, rout, out, As, Bs);
}

// ---------------- launch -----------------------------------------------------
extern "C" void kernel_launch(void* const* d_in, const int* in_sizes, int n_in,
                              void* d_out, int out_size, void* d_ws, size_t ws_size,
                              hipStream_t stream)
{
  (void)in_sizes; (void)n_in; (void)out_size; (void)ws_size;
  const float* x   = (const float*)d_in[0];
  const float* Wr  = (const float*)d_in[1];
  const float* Wg  = (const float*)d_in[2];
  const float* Wu  = (const float*)d_in[3];
  const float* Wd  = (const float*)d_in[4];
  const float* Wsg = (const float*)d_in[5];
  const float* Wsu = (const float*)d_in[6];
  const float* Wsd = (const float*)d_in[7];
  float* out = (float*)d_out;

  char* ws = (char*)d_ws;
  size_t off = 0;
  auto alloc = [&](size_t bytes) -> void* {
    void* p = ws + off; off += (bytes + 255) & ~(size_t)255; return p;
  };
  u16* xb    = (u16*)alloc((size_t)T * H * 2);
  u16* WsguT = (u16*)alloc((size_t)2 * DS * H * 2);   // [2048][1024] interleaved
  u16* WsdT  = (u16*)alloc((size_t)H * DS * 2);
  u16* WguT  = (u16*)alloc((size_t)E * 2 * D * H * 2); // per-e [1024][1024] interleaved
  u16* WdT   = (u16*)alloc((size_t)E * H * D * 2);
  u16* hs    = (u16*)alloc((size_t)T * DS * 2);
  u16* hr    = (u16*)alloc((size_t)PAIR_CAP * D * 2);
  u16* rout  = (u16*)alloc((size_t)PAIR_CAP * H * 2);
  int*   topk_idx  = (int*)alloc((size_t)T * 2 * 4);
  float* topk_w    = (float*)alloc((size_t)T * 2 * 4);
  int*   token_pos = (int*)alloc((size_t)T * 2 * 4);
  int*   partial_hist  = (int*)alloc((size_t)RB * 8 * 4);
  float* partial_probs = (float*)alloc((size_t)RB * 8 * 4);
  int*   block_offset  = (int*)alloc((size_t)RB * 8 * 4);
  int*   meta          = (int*)alloc(256);
  // zero-initialized region (dummy pair slots must read as 0)
  char* zbase = ws + off;
  int*   pair_token  = (int*)alloc((size_t)PAIR_CAP * 4);
  int*   pair_expert = (int*)alloc((size_t)PAIR_CAP * 4);
  float* pair_score  = (float*)alloc((size_t)PAIR_CAP * 4);
  size_t zbytes = (size_t)((ws + off) - zbase);

  hipMemsetAsync(zbase, 0, zbytes, stream);

  transpose_all<<<dim3(32, 32, 27), 256, 0, stream>>>(
      Wsg, Wsu, WsguT, Wsd, WsdT, Wg, Wu, WguT, Wd, WdT);

  router_kernel<<<RB, 256, 0, stream>>>(x, Wr, xb, topk_idx, topk_w,
                                        partial_hist, partial_probs);
  scan_kernel<<<1, 64, 0, stream>>>(partial_hist, partial_probs, block_offset,
                                    out + (size_t)T * H, meta);
  scatter_kernel<<<RB, 64, 0, stream>>>(topk_idx, topk_w, block_offset,
                                        pair_token, pair_expert, pair_score, token_pos);

  // fused gate+up (interleaved G/U): routed -> hr, shared -> hs
  gateup_fused<<<GU_ROUTED_BLKS + GU_SHARED_BLKS, 512, 0, stream>>>(
      xb, WguT, hr, WsguT, hs, pair_token, pair_expert, meta);

  // routed down -> rout [PAIR_CAP x H], scaled by pair score
  down_routed_kernel<<<DR_BLKS, 512, 0, stream>>>(
      hr, WdT, rout, pair_score, pair_expert, meta);
  // shared down + combine -> out [T x H] fp32
  down_shared_kernel<<<DSH_BLKS, 512, 0, stream>>>(
      hs, WsdT, rout, token_pos, out);
}

// Round 3
// 354.505 us; speedup vs baseline: 1.1882x; 1.0267x over previous
//
#include <hip/hip_runtime.h>

// MoE forward: shared SwiGLU expert + top-2/8 routed SwiGLU experts + aux loss.
// R9: (a) bijective chunked XCD swizzle (T1) on all GEMM grids -- consecutive
// tiles (ntile-fastest) land on one XCD so A panels are fetched once per XCD
// and B working set fits L2 (R8 decode replicated B across all 8 XCDs ->
// 111MB FETCH vs 38 ideal). (b) down GEMMs go BN=128 (B single-half):
// down_shared 128->256 blocks (was 50% CU idle), down_routed 288->576 (56->75%
// busy), LDS 96KB, vmcnt discipline recomputed (steady vmcnt(2)).
// (c) sched_barrier(0) both sides of each s_barrier. Pipeline structure
// (8-phase counted-vmcnt + setprio, m201-faithful double barrier) unchanged.

typedef unsigned short u16;
typedef unsigned int   u32;
typedef short short8 __attribute__((ext_vector_type(8)));
typedef float f32x4  __attribute__((ext_vector_type(4)));

#define AS1 __attribute__((address_space(1)))
#define AS3 __attribute__((address_space(3)))

constexpr int T  = 8192;
constexpr int H  = 1024;
constexpr int E  = 8;
constexpr int D  = 512;
constexpr int DS = 1024;          // shared expert width
constexpr int PAIR_CAP  = 18432;  // 72*256 >= 16384 + 8*255, 256-aligned
constexpr int MT_ROUTED = 72;     // routed m-tiles (256 rows each)
constexpr int RB = 512;           // router blocks (16 tokens each)

constexpr int GU_ROUTED_BLKS = 4 * MT_ROUTED;   // 288 (N=1024 interleaved, BN=256)
constexpr int GU_SHARED_BLKS = 8 * (T / 256);   // 256 (N=2048 interleaved, BN=256)
constexpr int GU_BLKS  = GU_ROUTED_BLKS + GU_SHARED_BLKS;  // 544 (div by 8)
constexpr int DR_BLKS  = 8 * MT_ROUTED;         // 576 (N=1024, BN=128)
constexpr int DSH_BLKS = 8 * (T / 256);         // 256 (N=1024, BN=128)

__device__ __forceinline__ u16 f2bf(float f){
  u32 u = __builtin_bit_cast(u32, f);
  u += 0x7fffu + ((u >> 16) & 1u);   // round-to-nearest-even
  return (u16)(u >> 16);
}
__device__ __forceinline__ float bf2f(u16 h){
  u32 u = ((u32)h) << 16;
  return __builtin_bit_cast(float, u);
}

// async global->LDS, 16B per lane. LDS dest = wave-uniform base + lane*16.
__device__ __forceinline__ void gl_lds16(const u16* g, u16* l){
  __builtin_amdgcn_global_load_lds((const AS1 void*)g, (AS3 void*)l, 16, 0, 0);
}

// s_waitcnt imm: vm[3:0] | exp=7<<4 | lgkm=15<<8 (vm high bits 0)
template<int N>
__device__ __forceinline__ void wait_vm(){ __builtin_amdgcn_s_waitcnt(0x0f70 | N); }

// RAW workgroup barrier, scheduling pinned on both sides (keep phase shape:
// no MFMA sinking past / ds_read hoisting across the barrier).
__device__ __forceinline__ void bar(){
  __builtin_amdgcn_sched_barrier(0);
  __builtin_amdgcn_s_barrier();
  __builtin_amdgcn_sched_barrier(0);
}

// Fragment read offset (elems) for logical chunk c at a row with row&7==lane&7.
__device__ __forceinline__ int swz_off(int c, int lane){
  return ((c ^ (lane & 7)) * 8);
}

// Bijective chunked XCD remap: blockIdx -> tile index tau such that
// consecutive tau (sharing A panels / few experts) land on one XCD
// (XCD id = blockIdx % 8 round-robin). Requires NWG % 8 == 0.
template<int NWG>
__device__ __forceinline__ int xcd_tau(int fid){
  return (fid & 7) * (NWG >> 3) + (fid >> 3);
}

// ---------------- router: logits -> softmax -> top2 + bf16 convert of x -----
__global__ void __launch_bounds__(256) router_kernel(
    const float* __restrict__ x, const float* __restrict__ Wr,
    u16* __restrict__ xb,
    int* __restrict__ topk_idx, float* __restrict__ topk_w,
    int* __restrict__ partial_hist, float* __restrict__ partial_probs)
{
  __shared__ int   hist_s[4][8];
  __shared__ float ps_s[4][8];
  int tid = threadIdx.x, lane = tid & 63, wv = tid >> 6;
  int   histl[8] = {0,0,0,0,0,0,0,0};
  float psl[8]   = {0.f,0.f,0.f,0.f,0.f,0.f,0.f,0.f};

  for (int it = 0; it < 4; ++it){
    int t = blockIdx.x * 16 + wv * 4 + it;
    const float4* xr = (const float4*)(x + (long)t * H);
    uint2* xbr = (uint2*)(xb + (long)t * H);
    float acc[8];
#pragma unroll
    for (int e = 0; e < 8; ++e) acc[e] = 0.f;
#pragma unroll
    for (int i = 0; i < 4; ++i){
      float4 xv = xr[i * 64 + lane];
      u32 lo = (u32)f2bf(xv.x) | ((u32)f2bf(xv.y) << 16);
      u32 hi = (u32)f2bf(xv.z) | ((u32)f2bf(xv.w) << 16);
      xbr[i * 64 + lane] = make_uint2(lo, hi);
      int h0 = i * 256 + lane * 4;
#pragma unroll
      for (int j = 0; j < 4; ++j){
        float xs = (j == 0) ? xv.x : (j == 1) ? xv.y : (j == 2) ? xv.z : xv.w;
        const float4* wr = (const float4*)(Wr + (long)(h0 + j) * E);
        float4 w0 = wr[0], w1 = wr[1];
        acc[0] += xs * w0.x; acc[1] += xs * w0.y; acc[2] += xs * w0.z; acc[3] += xs * w0.w;
        acc[4] += xs * w1.x; acc[5] += xs * w1.y; acc[6] += xs * w1.z; acc[7] += xs * w1.w;
      }
    }
#pragma unroll
    for (int off = 32; off >= 1; off >>= 1){
#pragma unroll
      for (int e = 0; e < 8; ++e) acc[e] += __shfl_xor(acc[e], off, 64);
    }
    if (lane == 0){
      float m = acc[0];
#pragma unroll
      for (int e = 1; e < 8; ++e) m = fmaxf(m, acc[e]);
      float p[8], s = 0.f;
#pragma unroll
      for (int e = 0; e < 8; ++e){ p[e] = __expf(acc[e] - m); s += p[e]; }
      float inv = 1.f / s;
#pragma unroll
      for (int e = 0; e < 8; ++e) psl[e] += p[e] * inv;
      int i1 = 0; float v1 = p[0];
#pragma unroll
      for (int e = 1; e < 8; ++e) if (p[e] > v1){ v1 = p[e]; i1 = e; }
      int i2 = -1; float v2 = -1.f;
#pragma unroll
      for (int e = 0; e < 8; ++e) if (e != i1 && p[e] > v2){ v2 = p[e]; i2 = e; }
      float rs = 1.f / (v1 + v2);
      topk_idx[2 * t] = i1; topk_idx[2 * t + 1] = i2;
      topk_w[2 * t] = v1 * rs; topk_w[2 * t + 1] = v2 * rs;
      histl[i1]++; histl[i2]++;
    }
  }
  if (lane == 0){
#pragma unroll
    for (int e = 0; e < 8; ++e){ hist_s[wv][e] = histl[e]; ps_s[wv][e] = psl[e]; }
  }
  __syncthreads();
  if (tid < 8){
    int hs = 0; float ps = 0.f;
#pragma unroll
    for (int w = 0; w < 4; ++w){ hs += hist_s[w][tid]; ps += ps_s[w][tid]; }
    partial_hist[blockIdx.x * 8 + tid]  = hs;
    partial_probs[blockIdx.x * 8 + tid] = ps;
  }
}

// ---------------- scan: 256-padded bases + per-block offsets + aux loss ------
__global__ void __launch_bounds__(64) scan_kernel(
    const int* __restrict__ partial_hist, const float* __restrict__ partial_probs,
    int* __restrict__ block_offset, float* __restrict__ out_aux,
    int* __restrict__ meta)
{
  __shared__ int   csum[8][8];
  __shared__ float cps[8][8];
  __shared__ int   cbase[8][8];
  __shared__ int   base_s[8];
  int tid = threadIdx.x, e = tid & 7, c = tid >> 3;
  int s = 0; float f = 0.f;
  for (int b = c * 64; b < c * 64 + 64; ++b){
    s += partial_hist[b * 8 + e]; f += partial_probs[b * 8 + e];
  }
  csum[c][e] = s; cps[c][e] = f;
  __syncthreads();
  if (tid < 8){
    int tot = 0;
    for (int cc = 0; cc < 8; ++cc){ cbase[cc][tid] = tot; tot += csum[cc][tid]; }
    csum[0][tid] = tot;            // column total (cbase already captured)
  }
  __syncthreads();
  if (tid == 0){
    int off = 0;
    for (int ee = 0; ee < 8; ++ee){ base_s[ee] = off; off += (csum[0][ee] + 255) & ~255; }
    meta[0] = off;                 // padded total (256-aligned)
    float a = 0.f;
    for (int ee = 0; ee < 8; ++ee){
      float ps = 0.f;
      for (int cc = 0; cc < 8; ++cc) ps += cps[cc][ee];
      float m = ps * (1.f / (float)T);
      a += m * m;
    }
    out_aux[0] = (float)E * a;
  }
  __syncthreads();
  int run = base_s[e] + cbase[c][e];
  for (int b = c * 64; b < c * 64 + 64; ++b){
    block_offset[b * 8 + e] = run;
    run += partial_hist[b * 8 + e];
  }
}

// ---------------- scatter: ballot-ranked, atomic-free ------------------------
__global__ void __launch_bounds__(64) scatter_kernel(
    const int* __restrict__ topk_idx, const float* __restrict__ topk_w,
    const int* __restrict__ block_offset,
    int* __restrict__ pair_token, int* __restrict__ pair_expert,
    float* __restrict__ pair_score, int* __restrict__ token_pos)
{
  int lane = threadIdx.x, b = blockIdx.x;
  if (lane >= 32) return;
  int idx = b * 32 + lane;
  int t = idx >> 1;
  int e = topk_idx[idx];
  float w = topk_w[idx];
  unsigned long long below = lane ? ((1ull << lane) - 1ull) : 0ull;
  int rank = 0, basee = 0;
#pragma unroll
  for (int ee = 0; ee < 8; ++ee){
    unsigned long long m = __ballot(e == ee);
    if (e == ee){ rank = __popcll(m & below); basee = block_offset[b * 8 + ee]; }
  }
  int pos = basee + rank;
  pair_token[pos] = t;
  pair_expert[pos] = e;
  pair_score[pos] = w;
  token_pos[idx] = pos;
}

// ---------------- all weight transposes in ONE launch ------------------------
// z: 0 Wsg->WsguT(lo), 1 Wsu->WsguT(hi), 2 Wsd->WsdT(plain),
//    [3,11) Wg->WguT(lo), [11,19) Wu->WguT(hi), [19,27) Wd->WdT(plain).
// Interleave: dst row for src col c: lo -> (c>>4)*32 + (c&15); hi -> +16.
__global__ void __launch_bounds__(256) transpose_all(
    const float* __restrict__ Wsg, const float* __restrict__ Wsu, u16* __restrict__ WsguT,
    const float* __restrict__ Wsd, u16* __restrict__ WsdT,
    const float* __restrict__ Wg,  const float* __restrict__ Wu, u16* __restrict__ WguT,
    const float* __restrict__ Wd,  u16* __restrict__ WdT)
{
  __shared__ float tile[32][33];
  int z = blockIdx.z;
  const float* src; u16* dst; int R, C, itype;
  if (z < 3){
    R = 1024; C = 1024;
    if (z == 0){ src = Wsg; dst = WsguT; itype = 1; }
    else if (z == 1){ src = Wsu; dst = WsguT; itype = 2; }
    else { src = Wsd; dst = WsdT; itype = 0; }
  } else if (z < 19){
    R = 1024; C = 512;
    int p = z - 3;
    if (p < 8){ src = Wg + (long)p * R * C; dst = WguT + (long)p * (2 * D * H); itype = 1; }
    else      { src = Wu + (long)(p - 8) * R * C; dst = WguT + (long)(p - 8) * (2 * D * H); itype = 2; }
  } else {
    R = 512; C = 1024;
    int p = z - 19;
    src = Wd + (long)p * R * C; dst = WdT + (long)p * R * C; itype = 0;
  }
  int tx = threadIdx.x & 31, ty = threadIdx.x >> 5;
  int c = blockIdx.x * 32 + tx;
  int rb = blockIdx.y * 32;
  if (blockIdx.x * 32 >= C || rb >= R) return;
#pragma unroll
  for (int j = 0; j < 4; ++j)
    tile[ty + j * 8][tx] = src[(long)(rb + ty + j * 8) * C + c];
  __syncthreads();
#pragma unroll
  for (int j = 0; j < 4; ++j){
    int cc = blockIdx.x * 32 + ty + j * 8;
    int dr = (itype == 0) ? cc : ((cc >> 4) * 32 + (cc & 15) + ((itype == 2) ? 16 : 0));
    dst[(long)dr * R + rb + tx] = f2bf(tile[tx][ty + j * 8]);
  }
}

// ---------------- 256xBN x64, 8-wave, 8-phase GEMM template ------------------
// BH = B half-count: 2 -> BN=256 (per-wave 128x64), 1 -> BN=128 (128x32).
// LDS: A 2buf x 2half x 16KB = 64KB; B 2buf x BH x 16KB (32 or 64KB).
// Stage schedule per K-tile t (4 quadrant phases qd):
//   qd0: A-half0(t+1)  qd1: A-half1(t+1)  qd2: B-half0(t+2)
//   qd3: [BH=2] B-half1(t+2); then vmcnt(2*BH)
// Steady state at qd3 wait: outstanding = B(t+1)[2BH] + A(t+1)[4] + B(t+2)[2BH]
// instrs; vmcnt(2*BH) drains A(t+1)/B(t+1), leaving only B(t+2) in flight.
// Tail: at t = NT-2 no B(t+2) issued -> vmcnt(0).
struct HalfStage { const u16* p[2]; };

__device__ __forceinline__ void half_init(HalfStage& hs, const u16* __restrict__ gbase,
    int ld, int rowbase, const int* __restrict__ gather, int wave, int lane){
  int lr = lane >> 3, ch = lane & 7;
  int chs = (ch ^ lr) * 8;         // swizzled source chunk (LDS stays linear)
#pragma unroll
  for (int j = 0; j < 2; ++j){
    int row = (wave * 2 + j) * 8 + lr;          // 0..127
    int grow = gather ? gather[rowbase + row] : (rowbase + row);
    hs.p[j] = gbase + (long)grow * ld + chs;
  }
}

__device__ __forceinline__ void half_issue(const HalfStage& hs, int k0,
                                           u16* __restrict__ lds, int wave){
#pragma unroll
  for (int j = 0; j < 2; ++j)
    gl_lds16(hs.p[j] + k0, lds + (wave * 2 + j) * 512);
}

// EPI: 0 = gateup (interleaved G/U, SwiGLU -> bf16 o_bf, ld o_ld; BH=2 only)
//      1 = down_routed (scale by pair_score -> bf16 rout)
//      2 = down_shared (+ combine via token_pos -> fp32 out)
template<int EPI, int BH>
__device__ __forceinline__ void gemm256(
    const u16* __restrict__ A, const u16* __restrict__ B, int K, int NT,
    const int* __restrict__ gather, int m0, int n0,
    u16* __restrict__ o_bf, int o_ld,
    const float* __restrict__ pair_score,
    const int* __restrict__ token_pos, const u16* __restrict__ rout,
    float* __restrict__ out,
    u16* __restrict__ As, u16* __restrict__ Bs)
{
  constexpr int NB = 2 * BH;       // per-wave B n-frags
  int tid = threadIdx.x, lane = tid & 63, wave = tid >> 6;
  int wm = wave >> 2, wn = wave & 3;
  int rl = lane & 15, q = lane >> 4;

  HalfStage a0, a1, b0, b1;
  half_init(a0, A, K, m0,       gather, wave, lane);
  half_init(a1, A, K, m0 + 128, gather, wave, lane);
  half_init(b0, B, K, n0,       nullptr, wave, lane);
  if (BH == 2) half_init(b1, B, K, n0 + 128, nullptr, wave, lane);

  f32x4 acc[8][NB];
#pragma unroll
  for (int i = 0; i < 8; ++i)
#pragma unroll
    for (int j = 0; j < NB; ++j)
#pragma unroll
      for (int r = 0; r < 4; ++r) acc[i][j][r] = 0.f;

  // prologue: tile0 fully + tile1 B halves; vmcnt(2*BH) -> tile0 landed
  half_issue(b0, 0, Bs + 0 * 8192, wave);
  if (BH == 2) half_issue(b1, 0, Bs + 1 * 8192, wave);
  half_issue(a0, 0, As + 0 * 8192, wave);
  half_issue(a1, 0, As + 1 * 8192, wave);
  if (NT > 1){
    half_issue(b0, 64, Bs + (BH + 0) * 8192, wave);
    if (BH == 2) half_issue(b1, 64, Bs + 3 * 8192, wave);
    wait_vm<2 * BH>();
  } else {
    wait_vm<0>();
  }
  bar();

  int bhalf = (BH == 2) ? (wn >> 1) : 0;
  int brow0 = (BH == 2) ? (wn & 1) * 64 : wn * 32;

#pragma unroll 1
  for (int t = 0; t < NT; ++t){
    int buf = t & 1, nbuf = buf ^ 1;
    const u16* Abase = As + (buf * 2 + wm) * 8192;
    const u16* Bbase = Bs + (buf * BH + bhalf) * 8192;
    short8 bfr[2][NB];
#pragma unroll
    for (int qd = 0; qd < 4; ++qd){
      // 1. ds-reads: A quadrant (4x b128); + all B frags at qd==0
      short8 afr[2][2];
#pragma unroll
      for (int ks = 0; ks < 2; ++ks){
        int off = swz_off(ks * 4 + q, lane);
#pragma unroll
        for (int m = 0; m < 2; ++m)
          afr[ks][m] = *(const short8*)(Abase + (qd * 32 + m * 16 + rl) * 64 + off);
        if (qd == 0){
#pragma unroll
          for (int n = 0; n < NB; ++n)
            bfr[ks][n] = *(const short8*)(Bbase + (brow0 + n * 16 + rl) * 64 + off);
        }
      }
      // 2. stage-issue per schedule
      if (qd == 0 && t + 1 < NT) half_issue(a0, (t + 1) * 64, As + (nbuf * 2 + 0) * 8192, wave);
      if (qd == 1 && t + 1 < NT) half_issue(a1, (t + 1) * 64, As + (nbuf * 2 + 1) * 8192, wave);
      if (qd == 2 && t + 2 < NT) half_issue(b0, (t + 2) * 64, Bs + (buf * BH + 0) * 8192, wave);
      if (BH == 2 && qd == 3 && t + 2 < NT) half_issue(b1, (t + 2) * 64, Bs + (buf * 2 + 1) * 8192, wave);
      // 3. raw barrier (pinned); compiler inserts fine-grained lgkm waits
      bar();
      // 4. MFMA cluster, T5 setprio
      __builtin_amdgcn_s_setprio(1);
#pragma unroll
      for (int ks = 0; ks < 2; ++ks)
#pragma unroll
        for (int m = 0; m < 2; ++m)
#pragma unroll
          for (int n = 0; n < NB; ++n)
            acc[qd * 2 + m][n] = __builtin_amdgcn_mfma_f32_16x16x32_bf16(
                afr[ks][m], bfr[ks][n], acc[qd * 2 + m][n], 0, 0, 0);
      __builtin_amdgcn_s_setprio(0);
      // 5. counted vmcnt once per K-tile (tail: full drain)
      if (qd == 3){
        if (t + 2 < NT) wait_vm<2 * BH>(); else wait_vm<0>();
      }
      bar();
    }
  }

  int row0 = m0 + wm * 128;
  if constexpr (EPI == 0){
    int hcol0 = (n0 >> 1) + wn * 32;
#pragma unroll
    for (int mt = 0; mt < 8; ++mt)
#pragma unroll
      for (int ntp = 0; ntp < 2; ++ntp)
#pragma unroll
        for (int r = 0; r < 4; ++r){
          int row = row0 + mt * 16 + q * 4 + r;
          int col = hcol0 + ntp * 16 + rl;
          float g = acc[mt][2 * ntp][r], u = acc[mt][2 * ntp + 1][r];
          float h = g / (1.f + __expf(-g)) * u;
          o_bf[(long)row * o_ld + col] = f2bf(h);
        }
  } else if constexpr (EPI == 1){
    int col0 = n0 + wn * (16 * NB);
#pragma unroll
    for (int mt = 0; mt < 8; ++mt)
#pragma unroll
      for (int r = 0; r < 4; ++r){
        int row = row0 + mt * 16 + q * 4 + r;
        float s = pair_score[row];
        long rbase = (long)row * H;
#pragma unroll
        for (int n = 0; n < NB; ++n){
          int col = col0 + n * 16 + rl;
          o_bf[rbase + col] = f2bf(s * acc[mt][n][r]);
        }
      }
  } else {
    int col0 = n0 + wn * (16 * NB);
#pragma unroll
    for (int mt = 0; mt < 8; ++mt)
#pragma unroll
      for (int r = 0; r < 4; ++r){
        int row = row0 + mt * 16 + q * 4 + r;
        int p0 = token_pos[2 * row], p1 = token_pos[2 * row + 1];
        long o = (long)row * H;
#pragma unroll
        for (int n = 0; n < NB; ++n){
          int col = col0 + n * 16 + rl;
          out[o + col] = acc[mt][n][r]
                       + bf2f(rout[(long)p0 * H + col])
                       + bf2f(rout[(long)p1 * H + col]);
        }
      }
  }
}

// ---------------- GEMM kernels ----------------------------------------------
__global__ void __launch_bounds__(512, 2) gateup_fused(
    const u16* __restrict__ xb, const u16* __restrict__ WguT, u16* __restrict__ hr,
    const u16* __restrict__ WsguT, u16* __restrict__ hs,
    const int* __restrict__ pair_token, const int* __restrict__ pair_expert,
    const int* __restrict__ meta)
{
  __shared__ u16 As[4 * 8192];
  __shared__ u16 Bs[4 * 8192];
  int tau = xcd_tau<GU_BLKS>(blockIdx.x);
  if (tau < GU_ROUTED_BLKS){
    int mtile = tau >> 2, ntile = tau & 3;       // ntile-fastest
    int m0 = mtile * 256;
    if (m0 >= meta[0]) return;                   // all-dummy tile
    int e = pair_expert[m0];
    gemm256<0, 2>(xb, WguT + (long)e * (2 * D * H), H, H / 64, pair_token,
                  m0, ntile * 256, hr, D, nullptr, nullptr, nullptr, nullptr, As, Bs);
  } else {
    int sidx = tau - GU_ROUTED_BLKS;
    int mtile = sidx >> 3, ntile = sidx & 7;
    gemm256<0, 2>(xb, WsguT, H, H / 64, nullptr,
                  mtile * 256, ntile * 256, hs, DS, nullptr, nullptr, nullptr, nullptr, As, Bs);
  }
}

__global__ void __launch_bounds__(512, 2) down_routed_kernel(
    const u16* __restrict__ hr, const u16* __restrict__ WdT, u16* __restrict__ rout,
    const float* __restrict__ pair_score, const int* __restrict__ pair_expert,
    const int* __restrict__ meta)
{
  __shared__ u16 As[4 * 8192];
  __shared__ u16 Bs[2 * 8192];
  int tau = xcd_tau<DR_BLKS>(blockIdx.x);
  int mtile = tau >> 3, ntile = tau & 7;         // BN=128: 8 ntiles
  int m0 = mtile * 256;
  if (m0 >= meta[0]) return;
  int e = pair_expert[m0];
  gemm256<1, 1>(hr, WdT + (long)e * (H * D), D, D / 64, nullptr,
                m0, ntile * 128, rout, H, pair_score, nullptr, nullptr, nullptr, As, Bs);
}

__global__ void __launch_bounds__(512, 2) down_shared_kernel(
    const u16* __restrict__ hs, const u16* __restrict__ WsdT,
    const u16* __restrict__ rout, const int* __restrict__ token_pos,
    float* __restrict__ out)
{
  __shared__ u16 As[4 * 8192];
  __shared__ u16 Bs[2 * 8192];
  int tau = xcd_tau<DSH_BLKS>(blockIdx.x);
  int mtile = tau >> 3, ntile = tau & 7;         // BN=128: 8 ntiles
  gemm256<2, 1>(hs, WsdT, DS, DS / 64, nullptr,
                mtile * 256, ntile * 128, nullptr, 0, nullptr, token_pos, rout, out, As, Bs);
}

// ---------------- launch -----------------------------------------------------
extern "C" void kernel_launch(void* const* d_in, const int* in_sizes, int n_in,
                              void* d_out, int out_size, void* d_ws, size_t ws_size,
                              hipStream_t stream)
{
  (void)in_sizes; (void)n_in; (void)out_size; (void)ws_size;
  const float* x   = (const float*)d_in[0];
  const float* Wr  = (const float*)d_in[1];
  const float* Wg  = (const float*)d_in[2];
  const float* Wu  = (const float*)d_in[3];
  const float* Wd  = (const float*)d_in[4];
  const float* Wsg = (const float*)d_in[5];
  const float* Wsu = (const float*)d_in[6];
  const float* Wsd = (const float*)d_in[7];
  float* out = (float*)d_out;

  char* ws = (char*)d_ws;
  size_t off = 0;
  auto alloc = [&](size_t bytes) -> void* {
    void* p = ws + off; off += (bytes + 255) & ~(size_t)255; return p;
  };
  u16* xb    = (u16*)alloc((size_t)T * H * 2);
  u16* WsguT = (u16*)alloc((size_t)2 * DS * H * 2);   // [2048][1024] interleaved
  u16* WsdT  = (u16*)alloc((size_t)H * DS * 2);
  u16* WguT  = (u16*)alloc((size_t)E * 2 * D * H * 2); // per-e [1024][1024] interleaved
  u16* WdT   = (u16*)alloc((size_t)E * H * D * 2);
  u16* hs    = (u16*)alloc((size_t)T * DS * 2);
  u16* hr    = (u16*)alloc((size_t)PAIR_CAP * D * 2);
  u16* rout  = (u16*)alloc((size_t)PAIR_CAP * H * 2);
  int*   topk_idx  = (int*)alloc((size_t)T * 2 * 4);
  float* topk_w    = (float*)alloc((size_t)T * 2 * 4);
  int*   token_pos = (int*)alloc((size_t)T * 2 * 4);
  int*   partial_hist  = (int*)alloc((size_t)RB * 8 * 4);
  float* partial_probs = (float*)alloc((size_t)RB * 8 * 4);
  int*   block_offset  = (int*)alloc((size_t)RB * 8 * 4);
  int*   meta          = (int*)alloc(256);
  // zero-initialized region (dummy pair slots must read as 0)
  char* zbase = ws + off;
  int*   pair_token  = (int*)alloc((size_t)PAIR_CAP * 4);
  int*   pair_expert = (int*)alloc((size_t)PAIR_CAP * 4);
  float* pair_score  = (float*)alloc((size_t)PAIR_CAP * 4);
  size_t zbytes = (size_t)((ws + off) - zbase);

  hipMemsetAsync(zbase, 0, zbytes, stream);

  transpose_all<<<dim3(32, 32, 27), 256, 0, stream>>>(
      Wsg, Wsu, WsguT, Wsd, WsdT, Wg, Wu, WguT, Wd, WdT);

  router_kernel<<<RB, 256, 0, stream>>>(x, Wr, xb, topk_idx, topk_w,
                                        partial_hist, partial_probs);
  scan_kernel<<<1, 64, 0, stream>>>(partial_hist, partial_probs, block_offset,
                                    out + (size_t)T * H, meta);
  scatter_kernel<<<RB, 64, 0, stream>>>(topk_idx, topk_w, block_offset,
                                        pair_token, pair_expert, pair_score, token_pos);

  // fused gate+up (interleaved G/U): routed -> hr, shared -> hs
  gateup_fused<<<GU_BLKS, 512, 0, stream>>>(
      xb, WguT, hr, WsguT, hs, pair_token, pair_expert, meta);

  // routed down -> rout [PAIR_CAP x H], scaled by pair score
  down_routed_kernel<<<DR_BLKS, 512, 0, stream>>>(
      hr, WdT, rout, pair_score, pair_expert, meta);
  // shared down + combine -> out [T x H] fp32
  down_shared_kernel<<<DSH_BLKS, 512, 0, stream>>>(
      hs, WsdT, rout, token_pos, out);
}